// Round 1
// baseline (159.456 us; speedup 1.0000x reference)
//
#include <hip/hip_runtime.h>
#include <math.h>

typedef float f4 __attribute__((ext_vector_type(4)));

// x: [B=4, A=64, S=64, C=64, F=64] fp32
// out[b,a,s,c,f] = x * att_c[b,c,f] * att_s[b,s,f] * att_a[b,a,f]

// ---------------- Stage 1: pooling ----------------
// grid = B*A = 256 blocks (one per [S,C,F] slab), block = 512 threads (8 waves)
// wave w handles s = sb*8 + w; lane = cg(2b)|fg(4b); thread loads f4 at f=fg*4.
__global__ __launch_bounds__(512) void pool_kernel(
    const float* __restrict__ x,
    float* __restrict__ partial_s,   // [B,A,S,F] = sum over c
    float* __restrict__ partial_c,   // [B,A,C,F] = sum over s
    float* __restrict__ m_a)         // [B,A,F]   = mean over (s,c)
{
    const int blk  = blockIdx.x;          // b*64 + a
    const int t    = threadIdx.x;
    const int w    = t >> 6;              // wave 0..7
    const int lane = t & 63;
    const int fg   = lane & 15;           // f = fg*4
    const int cg   = lane >> 4;           // 0..3: c-quarter

    const float* xb = x + (size_t)blk * (64 * 64 * 64);

    f4 csum[16];                          // c = cg*16 + j, summed over this wave's s
#pragma unroll
    for (int j = 0; j < 16; ++j) csum[j] = f4{0.f, 0.f, 0.f, 0.f};
    f4 areg = f4{0.f, 0.f, 0.f, 0.f};

    for (int sb = 0; sb < 8; ++sb) {
        const int s = sb * 8 + w;
        const float* xs = xb + s * (64 * 64) + cg * (16 * 64) + fg * 4;
        f4 ssum = f4{0.f, 0.f, 0.f, 0.f};
#pragma unroll
        for (int j = 0; j < 16; ++j) {
            f4 v = *(const f4*)(xs + j * 64);
            ssum += v;
            csum[j] += v;
        }
        // butterfly over cg (lane bits 4,5): full sum over all 64 c
#pragma unroll
        for (int i = 0; i < 4; ++i) ssum[i] += __shfl_xor(ssum[i], 16);
#pragma unroll
        for (int i = 0; i < 4; ++i) ssum[i] += __shfl_xor(ssum[i], 32);
        if (cg == 0)
            *(f4*)(partial_s + (size_t)blk * (64 * 64) + s * 64 + fg * 4) = ssum;
        areg += ssum;                     // same value on all lanes
    }

    __shared__ float smc[64][64];         // per-c sums (over all s)
    __shared__ float sma[8][64];          // per-wave (s,c)-sums per f

    // staged cross-wave accumulation of per-c sums (deterministic, no atomics)
    for (int w2 = 0; w2 < 8; ++w2) {
        if (w == w2) {
#pragma unroll
            for (int j = 0; j < 16; ++j) {
                float* p = &smc[cg * 16 + j][fg * 4];
                if (w2 == 0) *(f4*)p = csum[j];
                else {
                    f4 old = *(const f4*)p;
                    *(f4*)p = old + csum[j];
                }
            }
        }
        __syncthreads();
    }

    if (cg == 0) *(f4*)(&sma[w][fg * 4]) = areg;
    __syncthreads();

    if (t < 64) {
        float acc = 0.f;
#pragma unroll
        for (int w2 = 0; w2 < 8; ++w2) acc += sma[w2][t];
        m_a[(size_t)blk * 64 + t] = acc * (1.f / 4096.f);   // mean over s,c
    }

    // dump smc -> partial_c (4096 floats, 512 threads x 8 floats)
    {
        const float* sp = &smc[0][0];
        f4 v0 = *(const f4*)(sp + t * 8);
        f4 v1 = *(const f4*)(sp + t * 8 + 4);
        float* dst = partial_c + (size_t)blk * 4096 + t * 8;
        *(f4*)(dst) = v0;
        *(f4*)(dst + 4) = v1;
    }
}

// ---------------- Stage 2: reduce partials over a ----------------
// Outputs: m_s[b,s,f], m_c[b,c,f]. 2*B*64*F/4 = 8192 f4 outputs.
// grid = 256 blocks * 256 threads; 8 threads (a-groups) per output, shfl-reduced.
__global__ __launch_bounds__(256) void reduce_kernel(
    const float* __restrict__ partial_s,
    const float* __restrict__ partial_c,
    float* __restrict__ m_s, float* __restrict__ m_c)
{
    const int t  = threadIdx.x;
    const int og = t >> 3;                 // output within block (0..31)
    const int g  = t & 7;                  // a-group
    const int o  = blockIdx.x * 32 + og;   // global f4 output id (0..8191)
    const int half = o >> 12;              // 0 -> s-pool, 1 -> c-pool
    const int r  = o & 4095;               // f4 within [B,64,F]
    const int b  = r >> 10;
    const int df = r & 1023;               // (d*64+f)/4

    const float* src = (half ? partial_c : partial_s)
                     + (size_t)b * (64 * 64 * 64) + (size_t)df * 4;
    f4 acc = f4{0.f, 0.f, 0.f, 0.f};
#pragma unroll
    for (int i = 0; i < 8; ++i)
        acc += *(const f4*)(src + (size_t)(g * 8 + i) * 4096);

    // reduce over g (lane bits 0..2)
#pragma unroll
    for (int m = 1; m <= 4; m <<= 1)
#pragma unroll
        for (int i = 0; i < 4; ++i) acc[i] += __shfl_xor(acc[i], m);

    if (g == 0) {
        acc *= (1.f / 4096.f);             // /(A*C) or /(A*S), both 4096
        float* dst = (half ? m_c : m_s) + (size_t)b * 4096 + df * 4;
        *(f4*)dst = acc;
    }
}

// ---------------- Stage 3: per-filter squeeze-excite attention ----------------
// grid = 3*64 (axis, f), block = 64. z = relu(m @ w1) ; att = sigmoid(z @ w2).
__global__ __launch_bounds__(64) void attn_kernel(
    const float* __restrict__ m_a, const float* __restrict__ m_s, const float* __restrict__ m_c,
    const float* __restrict__ w1_a, const float* __restrict__ w1_s, const float* __restrict__ w1_c,
    const float* __restrict__ w2_a, const float* __restrict__ w2_s, const float* __restrict__ w2_c,
    float* __restrict__ att_a, float* __restrict__ att_s, float* __restrict__ att_c)
{
    const int axis = blockIdx.x >> 6;
    const int f    = blockIdx.x & 63;
    const float* m  = axis == 0 ? m_a  : (axis == 1 ? m_s  : m_c);
    const float* w1 = axis == 0 ? w1_a : (axis == 1 ? w1_s : w1_c);  // [F,64,16]
    const float* w2 = axis == 0 ? w2_a : (axis == 1 ? w2_s : w2_c);  // [F,16,64]
    float* att      = axis == 0 ? att_a : (axis == 1 ? att_s : att_c);

    __shared__ float w1ld[64][16];
    __shared__ float w2ld[16][64];
    __shared__ float mld[4][64];
    __shared__ float zld[4][16];
    const int t = threadIdx.x;

    {
        const f4* s1 = (const f4*)(w1 + (size_t)f * 1024);
        f4* d1 = (f4*)(&w1ld[0][0]);
        const f4* s2 = (const f4*)(w2 + (size_t)f * 1024);
        f4* d2 = (f4*)(&w2ld[0][0]);
#pragma unroll
        for (int i = 0; i < 4; ++i) { d1[t + 64 * i] = s1[t + 64 * i]; d2[t + 64 * i] = s2[t + 64 * i]; }
#pragma unroll
        for (int b = 0; b < 4; ++b) mld[b][t] = m[(size_t)(b * 64 + t) * 64 + f];
    }
    __syncthreads();
    {
        const int b = t >> 4, e = t & 15;
        float acc = 0.f;
#pragma unroll
        for (int d = 0; d < 64; ++d) acc += mld[b][d] * w1ld[d][e];
        zld[b][e] = fmaxf(acc, 0.f);
    }
    __syncthreads();
    {
        const int d = t;
#pragma unroll
        for (int b = 0; b < 4; ++b) {
            float acc = 0.f;
#pragma unroll
            for (int e = 0; e < 16; ++e) acc += zld[b][e] * w2ld[e][d];
            att[(size_t)(b * 64 + d) * 64 + f] = 1.f / (1.f + expf(-acc));
        }
    }
}

// ---------------- Stage 4: elementwise scale ----------------
// grid = B*A*8 = 2048 (8 s per block), block = 256. att tables staged in LDS.
__global__ __launch_bounds__(256) void scale_kernel(
    const float* __restrict__ x,
    const float* __restrict__ att_a, const float* __restrict__ att_s,
    const float* __restrict__ att_c,
    float* __restrict__ out)
{
    const int blk = blockIdx.x;
    const int sc  = blk & 7;
    const int a   = (blk >> 3) & 63;
    const int b   = blk >> 9;
    const int t   = threadIdx.x;
    const int fg  = t & 15;
    const int cq  = t >> 4;

    __shared__ float acl[64][68];   // +4 pad: rows shift 4 banks -> conflict-free
    __shared__ float asl[8][64];

    {
        const f4* srcc = (const f4*)(att_c + (size_t)b * 4096);
#pragma unroll
        for (int i = 0; i < 4; ++i) {
            int q = t + 256 * i;               // f4 id: c = q>>4, f = (q&15)*4
            f4 v = srcc[q];
            *(f4*)(&acl[q >> 4][(q & 15) * 4]) = v;
        }
        if (t < 128) {
            f4 v = *(const f4*)(att_s + (size_t)b * 4096 + sc * 512 + t * 4);
            *(f4*)(&asl[t >> 4][(t & 15) * 4]) = v;
        }
    }
    f4 aa = *(const f4*)(att_a + (size_t)b * 4096 + a * 64 + fg * 4);
    __syncthreads();

    const size_t base = (size_t)((b * 64 + a) * 64 + sc * 8) * 4096;
    const float* xb = x + base;
    float* ob = out + base;

    for (int sl = 0; sl < 8; ++sl) {
        f4 m0 = aa * *(const f4*)(&asl[sl][fg * 4]);
#pragma unroll
        for (int k = 0; k < 4; ++k) {
            const int c = k * 16 + cq;
            const size_t off = (size_t)(sl * 64 + c) * 64 + fg * 4;
            f4 v = *(const f4*)(xb + off);
            f4 acv = *(const f4*)(&acl[c][fg * 4]);
            *(f4*)(ob + off) = v * m0 * acv;
        }
    }
}

extern "C" void kernel_launch(void* const* d_in, const int* in_sizes, int n_in,
                              void* d_out, int out_size, void* d_ws, size_t ws_size,
                              hipStream_t stream)
{
    (void)in_sizes; (void)n_in; (void)out_size; (void)ws_size;
    const float* x    = (const float*)d_in[0];
    const float* w1_a = (const float*)d_in[1];
    const float* w1_s = (const float*)d_in[2];
    const float* w1_c = (const float*)d_in[3];
    const float* w2_a = (const float*)d_in[4];
    const float* w2_s = (const float*)d_in[5];
    const float* w2_c = (const float*)d_in[6];
    float* out = (float*)d_out;

    // Small tables (6 * 16384 floats = 384 KiB) in workspace.
    float* m_a   = (float*)d_ws;
    float* m_s   = m_a + 16384;
    float* m_c   = m_s + 16384;
    float* att_a = m_c + 16384;
    float* att_s = att_a + 16384;
    float* att_c = att_s + 16384;

    // Big partials (2 * 16 MiB) staged in d_out; fully consumed by stage 2
    // before stage 4 overwrites d_out (stream-ordered), then every element of
    // d_out is rewritten by stage 4 -> deterministic.
    float* partial_s = out;                  // [B,A,S,F]
    float* partial_c = out + 4 * 1024 * 1024; // [B,A,C,F]

    hipLaunchKernelGGL(pool_kernel,   dim3(256),  dim3(512), 0, stream,
                       x, partial_s, partial_c, m_a);
    hipLaunchKernelGGL(reduce_kernel, dim3(256),  dim3(256), 0, stream,
                       partial_s, partial_c, m_s, m_c);
    hipLaunchKernelGGL(attn_kernel,   dim3(192),  dim3(64),  0, stream,
                       m_a, m_s, m_c, w1_a, w1_s, w1_c, w2_a, w2_s, w2_c,
                       att_a, att_s, att_c);
    hipLaunchKernelGGL(scale_kernel,  dim3(2048), dim3(256), 0, stream,
                       x, att_a, att_s, att_c, out);
}